// Round 8
// baseline (157.299 us; speedup 1.0000x reference)
//
#include <hip/hip_runtime.h>
#include <hip/hip_bf16.h>
#include <math.h>

#define B_ 16
#define C_ 64
#define H_ 64
#define W_ 64
#define KSTEPS 18

typedef __attribute__((ext_vector_type(8))) short bf16x8;
typedef __attribute__((ext_vector_type(4))) short bf16x4;
typedef __attribute__((ext_vector_type(4))) float f32x4;

static __device__ __forceinline__ unsigned short f2b(float f) {
    __hip_bfloat16 h = __float2bfloat16(f);
    return *reinterpret_cast<unsigned short*>(&h);
}
static __device__ __forceinline__ float b2f(unsigned short u) {
    __hip_bfloat16 h;
    *reinterpret_cast<unsigned short*>(&h) = u;
    return __bfloat162float(h);
}

// ---------------------------------------------------------------------------
// prep: pack Wp (bf16, A-frag order) + bnp (f32 [plane][{inv,bias}][64]).
// mf 0-3 q (center tap), 4-7 k (3x3), 8-11 v (center tap). k idx = tap*64+c.
// ---------------------------------------------------------------------------
__global__ __launch_bounds__(64) void prep_kernel(
    const float* __restrict__ wq, const float* __restrict__ wk, const float* __restrict__ wv,
    const float* __restrict__ qg, const float* __restrict__ qb, const float* __restrict__ qm, const float* __restrict__ qv,
    const float* __restrict__ kg, const float* __restrict__ kb, const float* __restrict__ km, const float* __restrict__ kv,
    const float* __restrict__ vg, const float* __restrict__ vb, const float* __restrict__ vm, const float* __restrict__ vv,
    const float* __restrict__ og, const float* __restrict__ ob, const float* __restrict__ om, const float* __restrict__ ov,
    unsigned short* __restrict__ Wp, float* __restrict__ bnp)
{
    const int bid = blockIdx.x;
    const int lane = threadIdx.x;
    if (bid < 12 * KSTEPS) {
        const int mf = bid / KSTEPS;
        const int ks = bid % KSTEPS;
        const int r = lane & 15;
        bf16x8 u;
#pragma unroll
        for (int j = 0; j < 8; j++) {
            int k = ks * 32 + ((lane >> 4) << 3) + j;
            int tap = k >> 6;
            int c = k & 63;
            float w;
            if (mf < 4)      { int co = mf * 16 + r;        w = (tap == 4) ? wq[co * 64 + c] : 0.f; }
            else if (mf < 8) { int co = (mf - 4) * 16 + r;  w = wk[(co * 64 + c) * 9 + tap]; }
            else             { int co = (mf - 8) * 16 + r;  w = (tap == 4) ? wv[co * 64 + c] : 0.f; }
            u[j] = (short)f2b(w);
        }
        *reinterpret_cast<bf16x8*>(Wp + ((size_t)(mf * KSTEPS + ks) * 64 + lane) * 8) = u;
    } else {
        const int c = lane;
        const float* G[4] = {qg, kg, vg, og};
        const float* Bt[4] = {qb, kb, vb, ob};
        const float* M[4] = {qm, km, vm, om};
        const float* V[4] = {qv, kv, vv, ov};
#pragma unroll
        for (int p = 0; p < 4; p++) {
            float inv = G[p][c] * rsqrtf(V[p][c] + 1e-5f);
            bnp[p * 128 + c] = inv;
            bnp[p * 128 + 64 + c] = Bt[p][c] - M[p][c] * inv;
        }
    }
}

// ---------------------------------------------------------------------------
// xt: transpose x NCHW f32 -> xt[(b,h,w),c] bf16 (channel-fastest).
// Block = (b,h), 256 threads.  Both global sides coalesced; LDS [64][65] pad.
// ---------------------------------------------------------------------------
__global__ __launch_bounds__(256) void xt_kernel(
    const float* __restrict__ x, unsigned short* __restrict__ xt)
{
    __shared__ float ls[64][65];
    const int b = blockIdx.x >> 6;
    const int h = blockIdx.x & 63;
    const int tid = threadIdx.x;
    const int w = tid & 63;
    const int cg = tid >> 6;          // 0..3
#pragma unroll
    for (int cc = 0; cc < 16; cc++) {
        int c = cg * 16 + cc;
        ls[c][w] = x[((b * 64 + c) * 64 + h) * 64 + w];
    }
    __syncthreads();
    const int px = tid & 63;
    bf16x8 u0, u1;
#pragma unroll
    for (int j = 0; j < 8; j++) {
        u0[j] = (short)f2b(ls[cg * 16 + j][px]);
        u1[j] = (short)f2b(ls[cg * 16 + 8 + j][px]);
    }
    size_t base = ((size_t)((b * 64 + h) * 64 + px)) * 64 + cg * 16;
    *reinterpret_cast<bf16x8*>(xt + base) = u0;
    *reinterpret_cast<bf16x8*>(xt + base + 8) = u1;
}

// ---------------------------------------------------------------------------
// fused: per (b, output row h).  512 threads = 8 waves.
// Phase 0: stage x rows h-2..h+2 (cols -1..64, zero OOB) from xt into LDS,
//          XOR-swizzled (byte ^= (col&7)<<4).
// Phase 1: implicit GEMM, M=192 (q|k|v), N=192 (3 rows x 64 px), K=576.
//          wave = (mfg 0..3: 3 mf) x (nfg 0..1: 6 nf); acc 18 x f32x4.
// Phase 2: BN(+ReLU q,k) in-register; write k,v (3 rows, 66-px halo) and
//          q (row h) to LDS reusing the x-tile region; zero halo cols and
//          OOB rows (=> logit = pos-only, PV contribution 0: ref semantics).
// Phase 3: attention (px, head) threads; out = relu(bn_o(PV)).
// q/k/v never touch global memory.
// ---------------------------------------------------------------------------
#define KSM_OFF 0
#define VSM_OFF 25344
#define QSM_OFF 50688
__global__ __launch_bounds__(512, 4) void fused_kernel(
    const unsigned short* __restrict__ xt, const unsigned short* __restrict__ Wp,
    const float* __restrict__ bnp,
    const float* __restrict__ ph, const float* __restrict__ pw,
    float* __restrict__ out)
{
    __shared__ __align__(16) char smem[58880];   // xs (42240) then ksm/vsm/qsm
    __shared__ float bns[512];
    const int bid = blockIdx.x;
    const int b = bid >> 6;
    const int h = bid & 63;
    const int tid = threadIdx.x;

    // ---- phase 0: stage x tile ----
    for (int i = tid; i < 5 * 66 * 8; i += 512) {
        int ch  = i & 7;                 // 16B chunk (c = ch*8)
        int col = (i >> 3) % 66;
        int dy  = (i >> 3) / 66;         // 0..4
        int gh = h - 2 + dy, gw = col - 1;
        bf16x8 u = (bf16x8){0,0,0,0,0,0,0,0};
        if ((unsigned)gh < 64u && (unsigned)gw < 64u)
            u = *reinterpret_cast<const bf16x8*>(xt + ((size_t)((b * 64 + gh) * 64 + gw)) * 64 + ch * 8);
        int La = ((dy * 66 + col) * 64 + ch * 8) * 2;
        La ^= (col & 7) << 4;
        *reinterpret_cast<bf16x8*>(smem + La) = u;
    }
    bns[tid < 512 ? tid : 0] = bnp[tid < 512 ? tid : 0];
    __syncthreads();

    // ---- phase 1: GEMM ----
    const int wid = tid >> 6, lane = tid & 63;
    const int mfg = wid >> 1, nfg = wid & 1;
    const int t = lane & 15, q4 = lane >> 4;

    f32x4 acc[3][6];
#pragma unroll
    for (int m = 0; m < 3; m++)
#pragma unroll
        for (int n = 0; n < 6; n++) acc[m][n] = (f32x4){0.f, 0.f, 0.f, 0.f};

    for (int ks = 0; ks < KSTEPS; ks++) {
        const int tap = ks >> 1;
        const int dy = tap / 3, dx = tap - dy * 3;
        const int kb = (ks & 1) * 32 + q4 * 8;
        bf16x8 bf[6];
#pragma unroll
        for (int n = 0; n < 6; n++) {
            int p = (nfg * 6 + n) * 16 + t;     // 0..191
            int r = p >> 6, colw = p & 63;
            int col = colw + dx;                // 0..65
            int La = (((r + dy) * 66 + col) * 64 + kb) * 2;
            La ^= (col & 7) << 4;
            bf[n] = *reinterpret_cast<const bf16x8*>(smem + La);
        }
#pragma unroll
        for (int m = 0; m < 3; m++) {
            int mf = mfg * 3 + m;
            bf16x8 af = *reinterpret_cast<const bf16x8*>(Wp + ((size_t)(mf * KSTEPS + ks) * 64 + lane) * 8);
#pragma unroll
            for (int n = 0; n < 6; n++)
                acc[m][n] = __builtin_amdgcn_mfma_f32_16x16x32_bf16(af, bf[n], acc[m][n], 0, 0, 0);
        }
    }
    __syncthreads();   // xs fully consumed; region may be overwritten

    // ---- phase 2: epilogue into LDS ----
#pragma unroll
    for (int m = 0; m < 3; m++) {
        int mf = mfg * 3 + m;
        int plane = mf >> 2;                    // 0=q 1=k 2=v
        int c0 = (mf * 16 + q4 * 4) & 63;
        f32x4 inv  = *reinterpret_cast<const f32x4*>(&bns[plane * 128 + c0]);
        f32x4 bias = *reinterpret_cast<const f32x4*>(&bns[plane * 128 + 64 + c0]);
#pragma unroll
        for (int n = 0; n < 6; n++) {
            int p = (nfg * 6 + n) * 16 + t;
            int r = p >> 6, colw = p & 63;
            bf16x4 pack;
#pragma unroll
            for (int j = 0; j < 4; j++) {
                float val = acc[m][n][j] * inv[j] + bias[j];
                if (plane < 2) val = fmaxf(val, 0.f);
                pack[j] = (short)f2b(val);
            }
            if (plane == 0) {
                if (r == 1) {
                    int La = (colw * 64 + c0) * 2;
                    La ^= (colw & 7) << 4;
                    *reinterpret_cast<bf16x4*>(smem + QSM_OFF + La) = pack;
                }
            } else {
                int pxp = colw + 1;
                int La = ((r * 66 + pxp) * 64 + c0) * 2;
                La ^= (pxp & 7) << 4;
                *reinterpret_cast<bf16x4*>(smem + (plane == 1 ? KSM_OFF : VSM_OFF) + La) = pack;
            }
        }
    }
    __syncthreads();

    // ---- zero halo cols (pxp 0,65) and OOB rows ----
    const bf16x8 z8 = (bf16x8){0,0,0,0,0,0,0,0};
    for (int i = tid; i < 96; i += 512) {
        int buf = i & 1;
        int j = i >> 1;            // 0..47
        int ch = j & 7;
        int jj = j >> 3;           // 0..5
        int col = (jj & 1) ? 65 : 0;
        int rr = jj >> 1;          // 0..2
        int La = ((rr * 66 + col) * 64 + ch * 8) * 2;
        La ^= (col & 7) << 4;
        *reinterpret_cast<bf16x8*>(smem + (buf ? VSM_OFF : KSM_OFF) + La) = z8;
    }
    int rbad = (h == 0) ? 0 : ((h == 63) ? 2 : -1);
    if (rbad >= 0) {
        for (int i = tid; i < 66 * 8 * 2; i += 512) {
            int buf = i & 1;
            int j = i >> 1;
            int ch = j & 7;
            int col = j >> 3;      // 0..65
            int La = ((rbad * 66 + col) * 64 + ch * 8) * 2;
            La ^= (col & 7) << 4;
            *reinterpret_cast<bf16x8*>(smem + (buf ? VSM_OFF : KSM_OFF) + La) = z8;
        }
    }
    __syncthreads();

    // ---- phase 3: attention ----
    const int px = tid & 63;
    const int head = tid >> 6;
    const int cb = head * 8;

    float qf[8];
    {
        int Lq = (px * 64 + cb) * 2;
        Lq ^= (px & 7) << 4;
        bf16x8 q8 = *reinterpret_cast<const bf16x8*>(smem + QSM_OFF + Lq);
#pragma unroll
        for (int j = 0; j < 8; j++) qf[j] = b2f((unsigned short)q8[j]);
    }

    float A[3], Bx[3];
#pragma unroll
    for (int tt = 0; tt < 3; tt++) {
        float a = 0.f, bb = 0.f;
#pragma unroll
        for (int j = 0; j < 8; j++) {
            a  = fmaf(qf[j], ph[(cb + j) * 3 + tt], a);
            bb = fmaf(qf[j], pw[(cb + j) * 3 + tt], bb);
        }
        A[tt] = a; Bx[tt] = bb;
    }

    float logit[9];
#pragma unroll
    for (int dy = 0; dy < 3; dy++) {
#pragma unroll
        for (int dx = 0; dx < 3; dx++) {
            int pxp = px + dx;
            int La = ((dy * 66 + pxp) * 64 + cb) * 2;
            La ^= (pxp & 7) << 4;
            bf16x8 k8 = *reinterpret_cast<const bf16x8*>(smem + KSM_OFF + La);
            float qk = 0.f;
#pragma unroll
            for (int j = 0; j < 8; j++) qk = fmaf(qf[j], b2f((unsigned short)k8[j]), qk);
            logit[dy * 3 + dx] = qk + A[dy] + Bx[dx];
        }
    }

    float mx = logit[0];
#pragma unroll
    for (int tt = 1; tt < 9; tt++) mx = fmaxf(mx, logit[tt]);
    float e[9], sum = 0.f;
#pragma unroll
    for (int tt = 0; tt < 9; tt++) { e[tt] = __expf(logit[tt] - mx); sum += e[tt]; }
    float inv = 1.f / sum;

    float o[8];
#pragma unroll
    for (int j = 0; j < 8; j++) o[j] = 0.f;
#pragma unroll
    for (int dy = 0; dy < 3; dy++) {
#pragma unroll
        for (int dx = 0; dx < 3; dx++) {
            int pxp = px + dx;
            int La = ((dy * 66 + pxp) * 64 + cb) * 2;
            La ^= (pxp & 7) << 4;
            bf16x8 v8 = *reinterpret_cast<const bf16x8*>(smem + VSM_OFF + La);
            float w = e[dy * 3 + dx];
#pragma unroll
            for (int j = 0; j < 8; j++) o[j] = fmaf(w, b2f((unsigned short)v8[j]), o[j]);
        }
    }

#pragma unroll
    for (int j = 0; j < 8; j++) {
        int c = cb + j;
        float val = fmaxf(fmaf(o[j] * inv, bns[384 + c], bns[384 + 64 + c]), 0.f);
        out[((size_t)(b * C_ + c) * H_ + h) * W_ + px] = val;
    }
}

// ---------------------------------------------------------------------------
extern "C" void kernel_launch(void* const* d_in, const int* in_sizes, int n_in,
                              void* d_out, int out_size, void* d_ws, size_t ws_size,
                              hipStream_t stream)
{
    const float* x   = (const float*)d_in[0];
    const float* wq  = (const float*)d_in[1];
    const float* wk  = (const float*)d_in[2];
    const float* wv  = (const float*)d_in[3];
    const float* ph  = (const float*)d_in[4];
    const float* pw  = (const float*)d_in[5];
    const float* qg  = (const float*)d_in[6];
    const float* qb  = (const float*)d_in[7];
    const float* qm  = (const float*)d_in[8];
    const float* qv  = (const float*)d_in[9];
    const float* kg  = (const float*)d_in[10];
    const float* kb  = (const float*)d_in[11];
    const float* km  = (const float*)d_in[12];
    const float* kv  = (const float*)d_in[13];
    const float* vg  = (const float*)d_in[14];
    const float* vb  = (const float*)d_in[15];
    const float* vm  = (const float*)d_in[16];
    const float* vv  = (const float*)d_in[17];
    const float* og  = (const float*)d_in[18];
    const float* ob  = (const float*)d_in[19];
    const float* om  = (const float*)d_in[20];
    const float* ov  = (const float*)d_in[21];

    char* ws = (char*)d_ws;
    unsigned short* Wp = (unsigned short*)ws;                 // 221184 B
    float* bnp = (float*)(ws + 221184);                       // 2048 B
    unsigned short* xt = (unsigned short*)(ws + 223232);      // 8.39 MB

    prep_kernel<<<12 * KSTEPS + 1, 64, 0, stream>>>(
        wq, wk, wv, qg, qb, qm, qv, kg, kb, km, kv, vg, vb, vm, vv,
        og, ob, om, ov, Wp, bnp);

    xt_kernel<<<B_ * H_, 256, 0, stream>>>(x, xt);

    fused_kernel<<<B_ * H_, 512, 0, stream>>>(xt, Wp, bnp, ph, pw, (float*)d_out);
}